// Round 1
// 142.562 us; speedup vs baseline: 1.0016x; 1.0016x over previous
//
#include <hip/hip_runtime.h>

#define HH 128
#define WW 128
#define HWSZ (HH * WW)
#define CC 64
#define OO 64
#define BB 4
#define NOFF 18
#define KK 576          // C*9

// ws layout (dword offsets)
#define WS_BG     0                         // 72*64*4 = 18432 (deform weights, quad-packed)
#define WS_BGO    18432                     // 72*32*4 = 9216  (offset weights, quad-packed, N=32)
#define WS_SUMS   27648                     // 64
#define WS_SUMSQ  27712                     // 64
#define WS_YBUF   27776                     // 4*64*16384 = 4194304

typedef __attribute__((ext_vector_type(8))) short short8;
typedef __attribute__((ext_vector_type(4))) int int4v;
typedef __attribute__((ext_vector_type(4))) float f32x4;

__device__ inline unsigned bf16rne(float f) {
  unsigned u = __float_as_uint(f);
  u += 0x7fff + ((u >> 16) & 1);
  return u >> 16;
}

// One kernel: NHWC-bf16 transpose (blocks 0..511) + weight repack + stats zero
// (blocks 512..575).
// K order: k = t*64 + c. Pair k2 = t*32 + jj packs channels (2jj,2jj+1).
// Quad-packed B: k-quad g (k2 = g*4+j): Bg[(g*64+o)*4+j], Bgo[(g*32+o)*4+j].
__global__ __launch_bounds__(256) void prep_kernel(
    const float* __restrict__ x, const float* __restrict__ off_w,
    const float* __restrict__ dc_w, unsigned int* __restrict__ xTu,
    int* __restrict__ Bg, int* __restrict__ Bgo, float* __restrict__ sums) {
  int bid = blockIdx.x;
  if (bid < BB * HH) {
    __shared__ float T[CC][WW + 1];
    int b = bid >> 7, h = bid & 127;
    int tw = threadIdx.x & 127, th = threadIdx.x >> 7;
    const float* xp = x + (size_t)b * CC * HWSZ + h * WW;
#pragma unroll 8
    for (int i = 0; i < 32; ++i) {
      int c = i * 2 + th;
      T[c][tw] = xp[c * HWSZ + tw];
    }
    __syncthreads();
    int c2 = threadIdx.x & 31, wq = threadIdx.x >> 5;
    unsigned int* op = xTu + ((size_t)(b * HH + h) * WW) * 32;
#pragma unroll 8
    for (int i = 0; i < 16; ++i) {
      int w = i * 8 + wq;
      unsigned pk = bf16rne(T[2 * c2][w]) | (bf16rne(T[2 * c2 + 1][w]) << 16);
      op[w * 32 + c2] = pk;
    }
  } else {
    int pb = bid - BB * HH;
    int tid = pb * 256 + threadIdx.x;
    int stride = 64 * 256;
    for (int i = tid; i < 72 * 64 * 4; i += stride) {
      int j = i & 3, o = (i >> 2) & 63, g = i >> 8;
      int k2 = g * 4 + j, t = k2 >> 5, jj = k2 & 31;
      unsigned lo = bf16rne(dc_w[o * KK + (2 * jj) * 9 + t]);
      unsigned hi = bf16rne(dc_w[o * KK + (2 * jj + 1) * 9 + t]);
      Bg[i] = (int)(lo | (hi << 16));
    }
    for (int i = tid; i < 72 * 32 * 4; i += stride) {
      int j = i & 3, o = (i >> 2) & 31, g = i >> 7;
      int k2 = g * 4 + j, t = k2 >> 5, jj = k2 & 31;
      unsigned pk = 0;
      if (o < NOFF) {
        unsigned lo = bf16rne(off_w[o * KK + (2 * jj) * 9 + t]);
        unsigned hi = bf16rne(off_w[o * KK + (2 * jj + 1) * 9 + t]);
        pk = lo | (hi << 16);
      }
      Bgo[i] = (int)pk;
    }
    if (tid < 128) sums[tid] = 0.0f;   // sums + sumsq contiguous
  }
}

// ---- phase-3 gather pipeline macros ----------------------------------------
// Lane map: p8 = lane>>3 (pixel-in-group-of-8), cq = lane&7 (channel quad,
// dwords 4cq..4cq+3). Each corner load is global_load_dwordx4: 8 lanes cover
// one pixel's 128 B contiguously. Meta read is an 8-lane b128 broadcast.
#define G_ISSUE(i, TAP, TL, PH)                                               \
  int4v m##i, da##i, db##i, dc##i, dd##i;                                     \
  {                                                                           \
    int pxl_ = (PH) * 8 + p8;                                                 \
    m##i = *(const int4v*)&Mw[(pxl_ * 9 + (TAP)) * 4];                        \
    unsigned x_ = (unsigned)m##i.x, y_ = (unsigned)m##i.y;                    \
    da##i = *(const int4v*)&xbu[(x_ & 0xffffu) * 32 + cq4];                   \
    db##i = *(const int4v*)&xbu[(x_ >> 16) * 32 + cq4];                       \
    dc##i = *(const int4v*)&xbu[(y_ & 0xffffu) * 32 + cq4];                   \
    dd##i = *(const int4v*)&xbu[(y_ >> 16) * 32 + cq4];                       \
  }

#define G_BLEND(i, TL, PH)                                                    \
  {                                                                           \
    int pxl_ = (PH) * 8 + p8;                                                 \
    float w00_ = __uint_as_float(((unsigned)m##i.z) << 16);                   \
    float w01_ = __uint_as_float(((unsigned)m##i.z) & 0xffff0000u);           \
    float w10_ = __uint_as_float(((unsigned)m##i.w) << 16);                   \
    float w11_ = __uint_as_float(((unsigned)m##i.w) & 0xffff0000u);           \
    int4v pk_;                                                                \
    _Pragma("unroll")                                                         \
    for (int j = 0; j < 4; ++j) {                                             \
      float slo_ = w00_ * __uint_as_float(((unsigned)da##i[j]) << 16);        \
      slo_ = fmaf(w01_, __uint_as_float(((unsigned)db##i[j]) << 16), slo_);   \
      slo_ = fmaf(w10_, __uint_as_float(((unsigned)dc##i[j]) << 16), slo_);   \
      slo_ = fmaf(w11_, __uint_as_float(((unsigned)dd##i[j]) << 16), slo_);   \
      float shi_ = w00_ * __uint_as_float(((unsigned)da##i[j]) & 0xffff0000u);\
      shi_ = fmaf(w01_, __uint_as_float(((unsigned)db##i[j]) & 0xffff0000u), shi_);\
      shi_ = fmaf(w10_, __uint_as_float(((unsigned)dc##i[j]) & 0xffff0000u), shi_);\
      shi_ = fmaf(w11_, __uint_as_float(((unsigned)dd##i[j]) & 0xffff0000u), shi_);\
      pk_[j] = (int)__builtin_amdgcn_perm(__float_as_uint(shi_) + 0x8000u,    \
                                          __float_as_uint(slo_) + 0x8000u,    \
                                          0x07060302u);                       \
    }                                                                         \
    *(int4v*)&A[(p0 + pxl_) * 100 + (TL) * 32 + cq4] = pk_;                   \
  }

// Fused offset-conv + deform-conv + BN-stats. Block = 64 px x 4 waves; wave cg
// owns px tile [16cg,16cg+16) end-to-end. Barrier-free until the final
// cross-wave stats sum (all LDS regions wave-private; DS ops in-order per wave).
__global__ __launch_bounds__(256, 4) void fused_kernel(
    const unsigned int* __restrict__ xTu, const int* __restrict__ Bg,
    const int* __restrict__ Bgo, const float* __restrict__ off_b,
    const float* __restrict__ dc_b, float* __restrict__ ybuf,
    float* __restrict__ sums, float* __restrict__ sumsq) {
  __shared__ __align__(16) int A[4 * 16 * 100];   // 25.6 KB (also stats alias)
  __shared__ __align__(16) int M[4 * 144 * 4];    // 9.2 KB meta
  __shared__ float offL[4][NOFF][16];             // 4.6 KB offsets

  int cg = threadIdx.x >> 6, lane = threadIdx.x & 63;
  int b = blockIdx.x >> 8, rem = blockIdx.x & 255;
  int h = rem >> 1, w0 = (rem & 1) * 64;
  int hw0 = h * WW + w0;
  int p0 = cg * 16;
  int n16 = lane & 15, q = lane >> 4;
  int pg = lane >> 3, part = lane & 7;
  const unsigned int* xbu = xTu + (size_t)b * HWSZ * 32;

  // ---------- phase 1: offset conv (im2col copy + MFMA) ----------
  f32x4 acc2[2] = {f32x4{0, 0, 0, 0}, f32x4{0, 0, 0, 0}};
#pragma unroll 1
  for (int chunk = 0; chunk < 3; ++chunk) {
    int cy = h + chunk - 1;
    bool vy = (cy >= 0) && (cy < HH);
    int cys = min(max(cy, 0), HH - 1);
#pragma unroll
    for (int tl = 0; tl < 3; ++tl) {
#pragma unroll
      for (int i = 0; i < 2; ++i) {
        int px = i * 8 + pg;
        int cx = w0 + p0 + px + tl - 1;
        bool v = vy && (cx >= 0) && (cx < WW);
        int cxs = min(max(cx, 0), WW - 1);
        int4v val = *(const int4v*)&xbu[(cys * WW + cxs) * 32 + part * 4];
        if (!v) { val.x = 0; val.y = 0; val.z = 0; val.w = 0; }
        *(int4v*)&A[(p0 + px) * 100 + tl * 32 + part * 4] = val;
      }
    }
#pragma unroll 2
    for (int kk = 0; kk < 6; ++kk) {
      int4v av = *(const int4v*)&A[(p0 + n16) * 100 + kk * 16 + q * 4];
      short8 af = __builtin_bit_cast(short8, av);
      int g = chunk * 24 + kk * 4 + q;
#pragma unroll
      for (int nt = 0; nt < 2; ++nt) {
        int4v bv = *(const int4v*)&Bgo[(g * 32 + nt * 16 + n16) * 4];
        short8 bfr = __builtin_bit_cast(short8, bv);
        acc2[nt] = __builtin_amdgcn_mfma_f32_16x16x32_bf16(af, bfr, acc2[nt], 0, 0, 0);
      }
    }
  }
#pragma unroll
  for (int nt = 0; nt < 2; ++nt) {
    int o = nt * 16 + n16;
    if (o < NOFF) {
      float bv = off_b[o];
#pragma unroll
      for (int r = 0; r < 4; ++r) offL[cg][o][q * 4 + r] = acc2[nt][r] + bv;
    }
  }

  // ---------- phase 2: bilinear meta (wave-private) ----------
  int* Mw = M + cg * 144 * 4;
#pragma unroll
  for (int it = 0; it < 3; ++it) {
    int m = it * 64 + lane;
    if (m < 144) {
      int pxl = (unsigned)m / 9u;
      int t = m - pxl * 9;
      float dy = offL[cg][2 * t][pxl];
      float dx = offL[cg][2 * t + 1][pxl];
      float py = (float)(h + t / 3 - 1) + dy;
      float pxf = (float)(w0 + p0 + pxl + (t % 3) - 1) + dx;
      float fy0 = floorf(py), fx0 = floorf(pxf);
      float ay = py - fy0, ax = pxf - fx0;
      int iy0 = (int)fy0, ix0 = (int)fx0;
      int iy1 = iy0 + 1, ix1 = ix0 + 1;
      float wy0 = 1.0f - ay, wy1 = ay, wx0 = 1.0f - ax, wx1 = ax;
      if (!(iy0 >= 0 && iy0 < HH)) wy0 = 0.0f;
      if (!(iy1 >= 0 && iy1 < HH)) wy1 = 0.0f;
      if (!(ix0 >= 0 && ix0 < WW)) wx0 = 0.0f;
      if (!(ix1 >= 0 && ix1 < WW)) wx1 = 0.0f;
      int cy0 = min(max(iy0, 0), HH - 1), cy1 = min(max(iy1, 0), HH - 1);
      int cx0 = min(max(ix0, 0), WW - 1), cx1 = min(max(ix1, 0), WW - 1);
      int4v mv;
      mv.x = (cy0 * WW + cx0) | ((cy0 * WW + cx1) << 16);
      mv.y = (cy1 * WW + cx0) | ((cy1 * WW + cx1) << 16);
      mv.z = (int)(bf16rne(wy0 * wx0) | (bf16rne(wy0 * wx1) << 16));
      mv.w = (int)(bf16rne(wy1 * wx0) | (bf16rne(wy1 * wx1) << 16));
      *(int4v*)&Mw[m * 4] = mv;
    }
  }

  // ---------- phase 3: x4-gather pipeline + MFMA ----------
  int p8 = lane >> 3;            // pixel slot 0..7
  int cq4 = (lane & 7) * 4;      // channel-quad dword offset 0..28
  f32x4 acc[4] = {f32x4{0,0,0,0}, f32x4{0,0,0,0}, f32x4{0,0,0,0}, f32x4{0,0,0,0}};
#pragma unroll 1
  for (int chunk = 0; chunk < 3; ++chunk) {
    int tap0 = chunk * 3;
    // 6 gather iterations (3 taps x 2 pixel-halves), 2-deep pipeline:
    // 8 dwordx4 loads (8 KB/wave) in flight before the first blend consumes.
    G_ISSUE(0, tap0 + 0, 0, 0)
    G_ISSUE(1, tap0 + 0, 0, 1)
    G_ISSUE(2, tap0 + 1, 1, 0)
    G_BLEND(0, 0, 0)
    G_ISSUE(3, tap0 + 1, 1, 1)
    G_BLEND(1, 0, 1)
    G_ISSUE(4, tap0 + 2, 2, 0)
    G_BLEND(2, 1, 0)
    G_ISSUE(5, tap0 + 2, 2, 1)
    G_BLEND(3, 1, 1)
    G_BLEND(4, 2, 0)
    G_BLEND(5, 2, 1)
#pragma unroll 2
    for (int kk = 0; kk < 6; ++kk) {
      int4v av = *(const int4v*)&A[(p0 + n16) * 100 + kk * 16 + q * 4];
      short8 af = __builtin_bit_cast(short8, av);
      int g = chunk * 24 + kk * 4 + q;
#pragma unroll
      for (int nt = 0; nt < 4; ++nt) {
        int4v bv = *(const int4v*)&Bg[(g * 64 + nt * 16 + n16) * 4];
        short8 bfr = __builtin_bit_cast(short8, bv);
        acc[nt] = __builtin_amdgcn_mfma_f32_16x16x32_bf16(af, bfr, acc[nt], 0, 0, 0);
      }
    }
  }

  // ---------- epilogue: y store + stats (alias into own A region) ----------
  float* SW = (float*)&A[cg * 1600];
#pragma unroll
  for (int nt = 0; nt < 4; ++nt) {
    int o = nt * 16 + n16;
    float bv = dc_b[o];
    f32x4 r;
    float s = 0.0f, ss = 0.0f;
#pragma unroll
    for (int r0 = 0; r0 < 4; ++r0) {
      r[r0] = acc[nt][r0] + bv;
      s += r[r0];
      ss += r[r0] * r[r0];
    }
    *(f32x4*)(ybuf + (size_t)(b * OO + o) * HWSZ + hw0 + p0 + q * 4) = r;
    s += __shfl_xor(s, 16);  s += __shfl_xor(s, 32);
    ss += __shfl_xor(ss, 16); ss += __shfl_xor(ss, 32);
    if (lane < 16) {   // lane == n16
      SW[nt * 16 + lane] = s;
      SW[64 + nt * 16 + lane] = ss;
    }
  }
  __syncthreads();
  if (threadIdx.x < 64) {
    float ts = 0.0f, tq = 0.0f;
#pragma unroll
    for (int wv = 0; wv < 4; ++wv) {
      const float* Sv = (const float*)&A[wv * 1600];
      ts += Sv[threadIdx.x];
      tq += Sv[64 + threadIdx.x];
    }
    atomicAdd(&sums[threadIdx.x], ts);
    atomicAdd(&sumsq[threadIdx.x], tq);
  }
}

__global__ __launch_bounds__(256) void norm_kernel(
    const float* __restrict__ ybuf, const float* __restrict__ sums,
    const float* __restrict__ sumsq, const float* __restrict__ gamma,
    const float* __restrict__ beta, float* __restrict__ out) {
  int gid = blockIdx.x * 256 + threadIdx.x;
  int flat = gid << 2;
  int o = (flat >> 14) & 63;
  const float invN = 1.0f / (float)(BB * HWSZ);
  float mean = sums[o] * invN;
  float var = sumsq[o] * invN - mean * mean;
  float rstd = rsqrtf(var + 1e-5f);
  float g = gamma[o] * rstd;
  float bta = beta[o] - mean * g;
  float4 v = ((const float4*)ybuf)[gid];
  float4 r;
  r.x = fmaxf(v.x * g + bta, 0.0f);
  r.y = fmaxf(v.y * g + bta, 0.0f);
  r.z = fmaxf(v.z * g + bta, 0.0f);
  r.w = fmaxf(v.w * g + bta, 0.0f);
  ((float4*)out)[gid] = r;
}

extern "C" void kernel_launch(void* const* d_in, const int* in_sizes, int n_in,
                              void* d_out, int out_size, void* d_ws, size_t ws_size,
                              hipStream_t stream) {
  const float* x     = (const float*)d_in[0];
  const float* off_w = (const float*)d_in[1];
  const float* off_b = (const float*)d_in[2];
  const float* dc_w  = (const float*)d_in[3];
  const float* dc_b  = (const float*)d_in[4];
  const float* gamma = (const float*)d_in[5];
  const float* beta  = (const float*)d_in[6];
  float* ws = (float*)d_ws;
  int*   Bg     = (int*)(ws + WS_BG);
  int*   Bgo    = (int*)(ws + WS_BGO);
  float* sums   = ws + WS_SUMS;
  float* sumsq  = ws + WS_SUMSQ;
  float* ybuf   = ws + WS_YBUF;
  float* out = (float*)d_out;
  // d_out (16 MB fp32) doubles as NHWC-bf16 scratch (8 MB); dead until norm writes.
  unsigned int* xTu = (unsigned int*)d_out;

  prep_kernel<<<BB * HH + 64, 256, 0, stream>>>(x, off_w, dc_w, xTu, Bg, Bgo, sums);
  fused_kernel<<<BB * HWSZ / 64, 256, 0, stream>>>(xTu, Bg, Bgo, off_b, dc_b, ybuf, sums, sumsq);
  norm_kernel<<<BB * OO * HWSZ / (4 * 256), 256, 0, stream>>>(ybuf, sums, sumsq, gamma, beta, out);
}